// Round 1
// baseline (622.902 us; speedup 1.0000x reference)
//
#include <hip/hip_runtime.h>
#include <stdint.h>

// Problem constants
#define BROWS 16384
#define FDIM  2048
#define NCLS  14
#define ADIM  64
#define NCAT  2176   // 2048 (W_proj) + 14 (W_fc) + 114 zero pad -> 17 tiles of 128
#define QKN   1792   // 2*C*D

typedef __attribute__((ext_vector_type(8))) short bhalf8_t;   // 8 bf16 (4 VGPRs)
typedef __attribute__((ext_vector_type(4))) float f32x4_t;    // MFMA C/D frag

__device__ __forceinline__ unsigned short f2bf(float f) {
  unsigned int u = __builtin_bit_cast(unsigned int, f);
  u += 0x7fffu + ((u >> 16) & 1u);      // RNE
  return (unsigned short)(u >> 16);
}

__device__ __forceinline__ void gl_lds16(const void* g, void* l) {
  __builtin_amdgcn_global_load_lds(
      (const __attribute__((address_space(1))) unsigned int*)g,
      (__attribute__((address_space(3))) unsigned int*)l, 16, 0, 0);
}

// ---------------- elementwise prep ----------------

// cast n8*8 floats -> bf16, 8 per thread
__global__ void cast8_bf16(const float* __restrict__ src,
                           unsigned short* __restrict__ dst, int n8) {
  int t = blockIdx.x * 256 + threadIdx.x;
  if (t >= n8) return;
  const float4* s = (const float4*)src + 2 * (size_t)t;
  float4 a = s[0], b = s[1];
  bhalf8_t o;
  o[0] = f2bf(a.x); o[1] = f2bf(a.y); o[2] = f2bf(a.z); o[3] = f2bf(a.w);
  o[4] = f2bf(b.x); o[5] = f2bf(b.y); o[6] = f2bf(b.z); o[7] = f2bf(b.w);
  *((bhalf8_t*)dst + t) = o;
}

// build concatenated weight [NCAT, FDIM] bf16: rows 0..2047 = W_proj, 2048..2061 = W_fc, rest 0
__global__ void build_wcat(const float* __restrict__ Wp, const float* __restrict__ Wf,
                           unsigned short* __restrict__ dst) {
  int row = blockIdx.x;            // [0, NCAT)
  int c8 = threadIdx.x * 8;        // 256*8 == 2048
  const float* src = nullptr;
  if (row < 2048) src = Wp + (size_t)row * FDIM + c8;
  else if (row < 2048 + NCLS) src = Wf + (size_t)(row - 2048) * FDIM + c8;
  bhalf8_t o = {0,0,0,0,0,0,0,0};
  if (src) {
    float4 a = *(const float4*)src, b = *(const float4*)(src + 4);
    o[0] = f2bf(a.x); o[1] = f2bf(a.y); o[2] = f2bf(a.z); o[3] = f2bf(a.w);
    o[4] = f2bf(b.x); o[5] = f2bf(b.y); o[6] = f2bf(b.z); o[7] = f2bf(b.w);
  }
  *(bhalf8_t*)(dst + (size_t)row * FDIM + c8) = o;
}

__global__ void build_biascat(const float* __restrict__ bp, const float* __restrict__ bf,
                              float* __restrict__ dst) {
  int i = blockIdx.x * 256 + threadIdx.x;
  if (i >= NCAT) return;
  dst[i] = (i < 2048) ? bp[i] : ((i < 2048 + NCLS) ? bf[i - 2048] : 0.f);
}

// ---------------- MFMA GEMM: C[M,N] = A[M,K] * Bw[N,K]^T (+bias[col]) ----------------
// 128x128 tile, BK=64, 256 threads (4 waves 2x2), 16x16x32 bf16 MFMA.
// LDS row = 8 chunks of 16B; chunk stored at position (chunk ^ (row&7)) -> conflict-free
// ds_read_b128 while keeping global_load_lds destinations contiguous.
__global__ __launch_bounds__(256) void gemm_bt(
    const unsigned short* __restrict__ A, const unsigned short* __restrict__ Bw,
    const float* __restrict__ bias, float* __restrict__ C,
    int K, int lda, int ldb, int ldc)
{
  __shared__ unsigned short lA[128 * 64];
  __shared__ unsigned short lB[128 * 64];
  const int tid = threadIdx.x;
  const int lane = tid & 63, wv = tid >> 6;
  const int m = lane & 15, quad = lane >> 4;
  const size_t rowBase = (size_t)blockIdx.x * 128;
  const size_t colBase = (size_t)blockIdx.y * 128;
  const int m0 = (wv >> 1) * 64, n0 = (wv & 1) * 64;

  f32x4_t acc[4][4];
#pragma unroll
  for (int i = 0; i < 4; ++i)
#pragma unroll
    for (int j = 0; j < 4; ++j) acc[i][j] = (f32x4_t){0.f, 0.f, 0.f, 0.f};

  int sS[4];                 // 16B slot index in LDS tile
  size_t gA[4], gB[4];       // element offsets of the staged chunk
#pragma unroll
  for (int i = 0; i < 4; ++i) {
    int s = ((i * 4 + wv) << 6) + lane;   // [0,1024): 4 issues x 4 waves x 64 lanes
    int r = s >> 3, qp = s & 7;
    int q = qp ^ (r & 7);                 // global k-chunk held at slot qp
    sS[i] = s;
    gA[i] = (rowBase + r) * (size_t)lda + q * 8;
    gB[i] = (colBase + r) * (size_t)ldb + q * 8;
  }

  for (int kb = 0; kb < K; kb += 64) {
#pragma unroll
    for (int i = 0; i < 4; ++i) {
      gl_lds16(A + gA[i] + kb, &lA[sS[i] * 8]);
      gl_lds16(Bw + gB[i] + kb, &lB[sS[i] * 8]);
    }
    __syncthreads();   // drains vmcnt before barrier
#pragma unroll
    for (int ks = 0; ks < 2; ++ks) {
      const int qc = ks * 4 + quad;       // k-chunk this lane's fragment needs
      bhalf8_t af[4], bf[4];
#pragma unroll
      for (int mi = 0; mi < 4; ++mi) {
        int r = m0 + mi * 16 + m;
        af[mi] = *(const bhalf8_t*)&lA[(r * 8 + (qc ^ (r & 7))) * 8];
      }
#pragma unroll
      for (int ni = 0; ni < 4; ++ni) {
        int r = n0 + ni * 16 + m;
        bf[ni] = *(const bhalf8_t*)&lB[(r * 8 + (qc ^ (r & 7))) * 8];
      }
#pragma unroll
      for (int mi = 0; mi < 4; ++mi)
#pragma unroll
        for (int ni = 0; ni < 4; ++ni)
          acc[mi][ni] = __builtin_amdgcn_mfma_f32_16x16x32_bf16(af[mi], bf[ni], acc[mi][ni], 0, 0, 0);
    }
    __syncthreads();
  }

  // epilogue: C/D layout col = lane&15, row = quad*4 + reg
#pragma unroll
  for (int ni = 0; ni < 4; ++ni) {
    size_t gcol = colBase + n0 + ni * 16 + m;
    float bv = bias ? bias[gcol] : 0.f;
#pragma unroll
    for (int mi = 0; mi < 4; ++mi) {
      size_t grow = rowBase + m0 + mi * 16 + quad * 4;
#pragma unroll
      for (int r = 0; r < 4; ++r)
        C[(grow + r) * (size_t)ldc + gcol] = acc[mi][ni][r] + bv;
    }
  }
}

// ---------------- BatchNorm ----------------

__global__ void bn_stats(const float* __restrict__ h, float* __restrict__ cs,
                         float* __restrict__ cq) {
  int col = blockIdx.x * 256 + threadIdx.x;   // gridDim.x = 8 -> cols [0,2048)
  int r0 = blockIdx.y * 256;                  // gridDim.y = 64
  float s = 0.f, q = 0.f;
  for (int r = 0; r < 256; ++r) {
    float v = h[(size_t)(r0 + r) * NCAT + col];
    s += v; q += v * v;
  }
  atomicAdd(&cs[col], s);
  atomicAdd(&cq[col], q);
}

__global__ void bn_finalize(const float* __restrict__ cs, const float* __restrict__ cq,
                            const float* __restrict__ g, const float* __restrict__ bt,
                            float* __restrict__ scale, float* __restrict__ shift) {
  int c = blockIdx.x * 256 + threadIdx.x;
  if (c >= FDIM) return;
  const float inv = 1.f / (float)BROWS;
  float mu = cs[c] * inv;
  float var = cq[c] * inv - mu * mu;
  float sc = g[c] * rsqrtf(var + 1e-5f);
  scale[c] = sc;
  shift[c] = bt[c] - mu * sc;
}

// h_bf16 = bf16(relu(h*scale + shift)), reads ld=NCAT fp32, writes ld=FDIM bf16
__global__ void bn_apply(const float* __restrict__ h, const float* __restrict__ sc,
                         const float* __restrict__ sh, unsigned short* __restrict__ hb) {
  int t = blockIdx.x * 256 + threadIdx.x;   // grid 16384 -> t < 4194304
  int row = t >> 8;
  int c8 = (t & 255) << 3;
  const float4* s = (const float4*)(h + (size_t)row * NCAT + c8);
  float4 a = s[0], b = s[1];
  float4 s0 = *(const float4*)(sc + c8), s1 = *(const float4*)(sc + c8 + 4);
  float4 h0 = *(const float4*)(sh + c8), h1 = *(const float4*)(sh + c8 + 4);
  bhalf8_t o;
  o[0] = f2bf(fmaxf(a.x * s0.x + h0.x, 0.f));
  o[1] = f2bf(fmaxf(a.y * s0.y + h0.y, 0.f));
  o[2] = f2bf(fmaxf(a.z * s0.z + h0.z, 0.f));
  o[3] = f2bf(fmaxf(a.w * s0.w + h0.w, 0.f));
  o[4] = f2bf(fmaxf(b.x * s1.x + h1.x, 0.f));
  o[5] = f2bf(fmaxf(b.y * s1.y + h1.y, 0.f));
  o[6] = f2bf(fmaxf(b.z * s1.z + h1.z, 0.f));
  o[7] = f2bf(fmaxf(b.w * s1.w + h1.w, 0.f));
  *(bhalf8_t*)(hb + (size_t)row * FDIM + c8) = o;
}

// ---------------- attention epilogue: one wave per row ----------------
// attn = q k^T (14x14, K=64) via one 16x16 MFMA chain; diag subtract, max-|.| normalize,
// corr = attn @ sigmoid(logits); out = logits + gamma*corr.
__global__ __launch_bounds__(256) void attn_ep(
    const float* __restrict__ qk, const float* __restrict__ hcat,
    const float* __restrict__ gamma, float* __restrict__ out)
{
  const int lane = threadIdx.x & 63;
  const int wv = threadIdx.x >> 6;
  const int b = blockIdx.x * 4 + wv;
  const int m = lane & 15, quad = lane >> 4;
  const float* qrow = qk + (size_t)b * QKN;
  f32x4_t acc = (f32x4_t){0.f, 0.f, 0.f, 0.f};
#pragma unroll
  for (int ks = 0; ks < 2; ++ks) {
    bhalf8_t af = {0,0,0,0,0,0,0,0}, bf = {0,0,0,0,0,0,0,0};
    if (m < NCLS) {
      const float* qa = qrow + m * 64 + ks * 32 + quad * 8;  // q[b][m][k..k+8)
      float4 a0 = *(const float4*)qa,          a1 = *(const float4*)(qa + 4);
      float4 b0 = *(const float4*)(qa + 896),  b1 = *(const float4*)(qa + 900); // k[b][m][...]
      af[0] = f2bf(a0.x); af[1] = f2bf(a0.y); af[2] = f2bf(a0.z); af[3] = f2bf(a0.w);
      af[4] = f2bf(a1.x); af[5] = f2bf(a1.y); af[6] = f2bf(a1.z); af[7] = f2bf(a1.w);
      bf[0] = f2bf(b0.x); bf[1] = f2bf(b0.y); bf[2] = f2bf(b0.z); bf[3] = f2bf(b0.w);
      bf[4] = f2bf(b1.x); bf[5] = f2bf(b1.y); bf[6] = f2bf(b1.z); bf[7] = f2bf(b1.w);
    }
    acc = __builtin_amdgcn_mfma_f32_16x16x32_bf16(af, bf, acc, 0, 0, 0);
  }
  // acc[r] = attn[c = quad*4+r][e = m]
  float logit_e = (m < NCLS) ? hcat[(size_t)b * NCAT + 2048 + m] : 0.f;
  float sig = 1.f / (1.f + __expf(-logit_e));
  float corr[4];
#pragma unroll
  for (int r = 0; r < 4; ++r) {
    int c = quad * 4 + r;
    float diag = __shfl(acc[r], (lane & 48) + c, 64);  // attn[c][c] lives in same 16-lane group
    float a = acc[r] - diag;
    float av = (m < NCLS) ? fabsf(a) : 0.f;
    av = fmaxf(av, __shfl_xor(av, 1, 64));
    av = fmaxf(av, __shfl_xor(av, 2, 64));
    av = fmaxf(av, __shfl_xor(av, 4, 64));
    av = fmaxf(av, __shfl_xor(av, 8, 64));
    float v = (m < NCLS) ? (a / av) * sig : 0.f;
    v += __shfl_xor(v, 1, 64);
    v += __shfl_xor(v, 2, 64);
    v += __shfl_xor(v, 4, 64);
    v += __shfl_xor(v, 8, 64);
    corr[r] = v;
  }
  if (m == 0) {
#pragma unroll
    for (int r = 0; r < 4; ++r) {
      int c = quad * 4 + r;
      if (c < NCLS) {
        float lc = hcat[(size_t)b * NCAT + 2048 + c];
        out[(size_t)b * NCLS + c] = lc + gamma[c] * corr[r];
      }
    }
  }
}

// ---------------- launch ----------------

extern "C" void kernel_launch(void* const* d_in, const int* in_sizes, int n_in,
                              void* d_out, int out_size, void* d_ws, size_t ws_size,
                              hipStream_t stream) {
  const float* features = (const float*)d_in[0];
  const float* W_proj   = (const float*)d_in[1];
  const float* b_proj   = (const float*)d_in[2];
  const float* bn_gamma = (const float*)d_in[3];
  const float* bn_beta  = (const float*)d_in[4];
  const float* W_qk     = (const float*)d_in[5];
  const float* gamma    = (const float*)d_in[6];
  const float* W_fc     = (const float*)d_in[7];
  const float* b_fc     = (const float*)d_in[8];
  float* out = (float*)d_out;

  char* ws = (char*)d_ws;
  unsigned short* featC   = (unsigned short*)ws;                 // 67,108,864 B
  unsigned short* WcatC   = (unsigned short*)(ws + 67108864);    //  8,912,896 B
  unsigned short* WqkC    = (unsigned short*)(ws + 76021760);    //  7,340,032 B
  float*          biasCat = (float*)(ws + 83361792);             //     16,384 B (8704 used)
  float*          hcat    = (float*)(ws + 83378176);             // 142,606,336 B
  float*          qkbuf   = (float*)(ws + 225984512);            // 117,440,512 B
  float*          colsum  = (float*)(ws + 343425024);            //      8,192 B
  float*          colsq   = (float*)(ws + 343433216);            //      8,192 B
  float*          scalev  = (float*)(ws + 343441408);            //      8,192 B
  float*          shiftv  = (float*)(ws + 343449600);            //      8,192 B  (total 343,457,792)
  unsigned short* hb = featC;   // features cast is dead after GEMM1 -> reuse for h_bf16

  // prep casts
  cast8_bf16<<<16384, 256, 0, stream>>>(features, featC, (BROWS * FDIM) / 8);
  build_wcat<<<NCAT, 256, 0, stream>>>(W_proj, W_fc, WcatC);
  cast8_bf16<<<1792, 256, 0, stream>>>(W_qk, WqkC, (QKN * FDIM) / 8);
  build_biascat<<<9, 256, 0, stream>>>(b_proj, b_fc, biasCat);

  // GEMM1: h_cat[B, 2176] = features @ [W_proj; W_fc; 0]^T + bias_cat
  gemm_bt<<<dim3(BROWS / 128, NCAT / 128), 256, 0, stream>>>(
      featC, WcatC, biasCat, hcat, FDIM, FDIM, FDIM, NCAT);

  // BatchNorm over cols [0,2048)
  hipMemsetAsync(colsum, 0, 16384, stream);  // colsum + colsq (adjacent)
  bn_stats<<<dim3(8, 64), 256, 0, stream>>>(hcat, colsum, colsq);
  bn_finalize<<<8, 256, 0, stream>>>(colsum, colsq, bn_gamma, bn_beta, scalev, shiftv);
  bn_apply<<<16384, 256, 0, stream>>>(hcat, scalev, shiftv, hb);

  // GEMM2: qk[B, 1792] = h @ W_qk^T
  gemm_bt<<<dim3(BROWS / 128, QKN / 128), 256, 0, stream>>>(
      hb, WqkC, nullptr, qkbuf, FDIM, FDIM, FDIM, QKN);

  // attention epilogue (one wave per row)
  attn_ep<<<BROWS / 4, 256, 0, stream>>>(qkbuf, hcat, gamma, out);
}

// Round 2
// 619.516 us; speedup vs baseline: 1.0055x; 1.0055x over previous
//
#include <hip/hip_runtime.h>
#include <stdint.h>

// Problem constants
#define BROWS 16384
#define FDIM  2048
#define NCLS  14
#define ADIM  64
#define NCAT  2176   // 2048 (W_proj) + 14 (W_fc) + 114 zero pad -> 17 tiles of 128
#define QKN   1792   // 2*C*D

typedef __attribute__((ext_vector_type(8))) short bhalf8_t;   // 8 bf16 (4 VGPRs)
typedef __attribute__((ext_vector_type(4))) float f32x4_t;    // MFMA C/D frag

__device__ __forceinline__ unsigned short f2bf(float f) {
  unsigned int u = __builtin_bit_cast(unsigned int, f);
  u += 0x7fffu + ((u >> 16) & 1u);      // RNE
  return (unsigned short)(u >> 16);
}
__device__ __forceinline__ float bf2f(unsigned short s) {
  return __builtin_bit_cast(float, (unsigned int)s << 16);
}

__device__ __forceinline__ void gl_lds16(const void* g, void* l) {
  __builtin_amdgcn_global_load_lds(
      (const __attribute__((address_space(1))) unsigned int*)g,
      (__attribute__((address_space(3))) unsigned int*)l, 16, 0, 0);
}

// ---------------- elementwise prep ----------------

// cast n8*8 floats -> bf16, 8 per thread
__global__ void cast8_bf16(const float* __restrict__ src,
                           unsigned short* __restrict__ dst, int n8) {
  int t = blockIdx.x * 256 + threadIdx.x;
  if (t >= n8) return;
  const float4* s = (const float4*)src + 2 * (size_t)t;
  float4 a = s[0], b = s[1];
  bhalf8_t o;
  o[0] = f2bf(a.x); o[1] = f2bf(a.y); o[2] = f2bf(a.z); o[3] = f2bf(a.w);
  o[4] = f2bf(b.x); o[5] = f2bf(b.y); o[6] = f2bf(b.z); o[7] = f2bf(b.w);
  *((bhalf8_t*)dst + t) = o;
}

// build concatenated weight [NCAT, FDIM] bf16: rows 0..2047 = W_proj, 2048..2061 = W_fc, rest 0
__global__ void build_wcat(const float* __restrict__ Wp, const float* __restrict__ Wf,
                           unsigned short* __restrict__ dst) {
  int row = blockIdx.x;            // [0, NCAT)
  int c8 = threadIdx.x * 8;        // 256*8 == 2048
  const float* src = nullptr;
  if (row < 2048) src = Wp + (size_t)row * FDIM + c8;
  else if (row < 2048 + NCLS) src = Wf + (size_t)(row - 2048) * FDIM + c8;
  bhalf8_t o = {0,0,0,0,0,0,0,0};
  if (src) {
    float4 a = *(const float4*)src, b = *(const float4*)(src + 4);
    o[0] = f2bf(a.x); o[1] = f2bf(a.y); o[2] = f2bf(a.z); o[3] = f2bf(a.w);
    o[4] = f2bf(b.x); o[5] = f2bf(b.y); o[6] = f2bf(b.z); o[7] = f2bf(b.w);
  }
  *(bhalf8_t*)(dst + (size_t)row * FDIM + c8) = o;
}

// ---------------- MFMA GEMM: bf16 out, optional fused bias + BN stats + logits ----------------
// 128x128 tile, BK=64, 256 threads (4 waves 2x2), 16x16x32 bf16 MFMA.
// LDS row = 8 chunks of 16B; chunk stored at slot (chunk ^ (row&7)) -> conflict-free
// ds_read_b128 while keeping global_load_lds destinations contiguous.
// MODE 0 (GEMM1): cols<2048 -> bf16 h store + bias(bp) + BN sum/sumsq atomics;
//                 col-block 16 -> fp32 logits[B,16] store + bias(bfc). ldc applies to bf16 h.
// MODE 1 (GEMM2): plain bf16 store, no bias.
template<int MODE>
__global__ __launch_bounds__(256) void gemm_bt(
    const unsigned short* __restrict__ A, const unsigned short* __restrict__ Bw,
    const float* __restrict__ bp, const float* __restrict__ bfc,
    unsigned short* __restrict__ Cb, float* __restrict__ logits,
    float* __restrict__ colsum, float* __restrict__ colsq,
    int K, int lda, int ldb, int ldc)
{
  __shared__ unsigned short lA[128 * 64];
  __shared__ unsigned short lB[128 * 64];
  const int tid = threadIdx.x;
  const int lane = tid & 63, wv = tid >> 6;
  const int m = lane & 15, quad = lane >> 4;
  const size_t rowBase = (size_t)blockIdx.x * 128;
  const size_t colBase = (size_t)blockIdx.y * 128;
  const int m0 = (wv >> 1) * 64, n0 = (wv & 1) * 64;

  f32x4_t acc[4][4];
#pragma unroll
  for (int i = 0; i < 4; ++i)
#pragma unroll
    for (int j = 0; j < 4; ++j) acc[i][j] = (f32x4_t){0.f, 0.f, 0.f, 0.f};

  int sS[4];                 // 16B slot index in LDS tile
  size_t gA[4], gB[4];       // element offsets of the staged chunk
#pragma unroll
  for (int i = 0; i < 4; ++i) {
    int s = ((i * 4 + wv) << 6) + lane;   // [0,1024): 4 issues x 4 waves x 64 lanes
    int r = s >> 3, qp = s & 7;
    int q = qp ^ (r & 7);                 // global k-chunk held at slot qp
    sS[i] = s;
    gA[i] = (rowBase + r) * (size_t)lda + q * 8;
    gB[i] = (colBase + r) * (size_t)ldb + q * 8;
  }

  for (int kb = 0; kb < K; kb += 64) {
#pragma unroll
    for (int i = 0; i < 4; ++i) {
      gl_lds16(A + gA[i] + kb, &lA[sS[i] * 8]);
      gl_lds16(Bw + gB[i] + kb, &lB[sS[i] * 8]);
    }
    __syncthreads();   // drains vmcnt before barrier
#pragma unroll
    for (int ks = 0; ks < 2; ++ks) {
      const int qc = ks * 4 + quad;       // k-chunk this lane's fragment needs
      bhalf8_t af[4], bf[4];
#pragma unroll
      for (int mi = 0; mi < 4; ++mi) {
        int r = m0 + mi * 16 + m;
        af[mi] = *(const bhalf8_t*)&lA[(r * 8 + (qc ^ (r & 7))) * 8];
      }
#pragma unroll
      for (int ni = 0; ni < 4; ++ni) {
        int r = n0 + ni * 16 + m;
        bf[ni] = *(const bhalf8_t*)&lB[(r * 8 + (qc ^ (r & 7))) * 8];
      }
#pragma unroll
      for (int mi = 0; mi < 4; ++mi)
#pragma unroll
        for (int ni = 0; ni < 4; ++ni)
          acc[mi][ni] = __builtin_amdgcn_mfma_f32_16x16x32_bf16(af[mi], bf[ni], acc[mi][ni], 0, 0, 0);
    }
    __syncthreads();
  }

  // epilogue: C/D layout col = lane&15, row = quad*4 + reg
  if (MODE == 0) {
    if (colBase < 2048) {
#pragma unroll
      for (int ni = 0; ni < 4; ++ni) {
        int gcol = (int)colBase + n0 + ni * 16 + m;
        float bv = bp[gcol];
        float s = 0.f, q = 0.f;
#pragma unroll
        for (int mi = 0; mi < 4; ++mi) {
          size_t grow = rowBase + m0 + mi * 16 + quad * 4;
#pragma unroll
          for (int r = 0; r < 4; ++r) {
            float v = acc[mi][ni][r] + bv;
            Cb[(grow + r) * (size_t)ldc + gcol] = f2bf(v);
            s += v; q += v * v;
          }
        }
        // reduce over quads (lanes m, m+16, m+32, m+48 share gcol, disjoint rows)
        s += __shfl_xor(s, 16, 64); s += __shfl_xor(s, 32, 64);
        q += __shfl_xor(q, 16, 64); q += __shfl_xor(q, 32, 64);
        if (quad == 0) { atomicAdd(&colsum[gcol], s); atomicAdd(&colsq[gcol], q); }
      }
    } else if (n0 == 0) {    // logits block: rel cols 0..15 only (ni==0 group)
      float bv = (m < NCLS) ? bfc[m] : 0.f;
#pragma unroll
      for (int mi = 0; mi < 4; ++mi) {
        size_t grow = rowBase + m0 + mi * 16 + quad * 4;
#pragma unroll
        for (int r = 0; r < 4; ++r)
          logits[(grow + r) * 16 + m] = acc[mi][0][r] + bv;
      }
    }
  } else {
#pragma unroll
    for (int ni = 0; ni < 4; ++ni) {
      int gcol = (int)colBase + n0 + ni * 16 + m;
#pragma unroll
      for (int mi = 0; mi < 4; ++mi) {
        size_t grow = rowBase + m0 + mi * 16 + quad * 4;
#pragma unroll
        for (int r = 0; r < 4; ++r)
          Cb[(grow + r) * (size_t)ldc + gcol] = f2bf(acc[mi][ni][r]);
      }
    }
  }
}

// ---------------- BatchNorm ----------------

__global__ void bn_finalize(const float* __restrict__ cs, const float* __restrict__ cq,
                            const float* __restrict__ g, const float* __restrict__ bt,
                            float* __restrict__ scale, float* __restrict__ shift) {
  int c = blockIdx.x * 256 + threadIdx.x;
  if (c >= FDIM) return;
  const float inv = 1.f / (float)BROWS;
  float mu = cs[c] * inv;
  float var = cq[c] * inv - mu * mu;
  float sc = g[c] * rsqrtf(var + 1e-5f);
  scale[c] = sc;
  shift[c] = bt[c] - mu * sc;
}

// in-place: h = bf16(relu(h*scale + shift)), bf16 [B, FDIM]
__global__ void bn_apply(unsigned short* __restrict__ hb, const float* __restrict__ sc,
                         const float* __restrict__ sh) {
  int t = blockIdx.x * 256 + threadIdx.x;   // grid 16384 -> t < 4194304
  int row = t >> 8;
  int c8 = (t & 255) << 3;
  unsigned short* p = hb + (size_t)row * FDIM + c8;
  bhalf8_t v = *(bhalf8_t*)p;
  float4 s0 = *(const float4*)(sc + c8), s1 = *(const float4*)(sc + c8 + 4);
  float4 h0 = *(const float4*)(sh + c8), h1 = *(const float4*)(sh + c8 + 4);
  bhalf8_t o;
  o[0] = f2bf(fmaxf(bf2f((unsigned short)v[0]) * s0.x + h0.x, 0.f));
  o[1] = f2bf(fmaxf(bf2f((unsigned short)v[1]) * s0.y + h0.y, 0.f));
  o[2] = f2bf(fmaxf(bf2f((unsigned short)v[2]) * s0.z + h0.z, 0.f));
  o[3] = f2bf(fmaxf(bf2f((unsigned short)v[3]) * s0.w + h0.w, 0.f));
  o[4] = f2bf(fmaxf(bf2f((unsigned short)v[4]) * s1.x + h1.x, 0.f));
  o[5] = f2bf(fmaxf(bf2f((unsigned short)v[5]) * s1.y + h1.y, 0.f));
  o[6] = f2bf(fmaxf(bf2f((unsigned short)v[6]) * s1.z + h1.z, 0.f));
  o[7] = f2bf(fmaxf(bf2f((unsigned short)v[7]) * s1.w + h1.w, 0.f));
  *(bhalf8_t*)p = o;
}

// ---------------- attention epilogue: one wave per row ----------------
// attn = q k^T (14x14, K=64) via 16x16 MFMA chain on bf16 qk; diag subtract,
// max-|.| normalize, corr = attn @ sigmoid(logits); out = logits + gamma*corr.
__global__ __launch_bounds__(256) void attn_ep(
    const unsigned short* __restrict__ qk, const float* __restrict__ logits,
    const float* __restrict__ gamma, float* __restrict__ out)
{
  const int lane = threadIdx.x & 63;
  const int wv = threadIdx.x >> 6;
  const int b = blockIdx.x * 4 + wv;
  const int m = lane & 15, quad = lane >> 4;
  const unsigned short* qrow = qk + (size_t)b * QKN;
  f32x4_t acc = (f32x4_t){0.f, 0.f, 0.f, 0.f};
#pragma unroll
  for (int ks = 0; ks < 2; ++ks) {
    bhalf8_t af = {0,0,0,0,0,0,0,0}, bf = {0,0,0,0,0,0,0,0};
    if (m < NCLS) {
      af = *(const bhalf8_t*)(qrow + m * 64 + ks * 32 + quad * 8);        // q[b][m][k..k+8)
      bf = *(const bhalf8_t*)(qrow + 896 + m * 64 + ks * 32 + quad * 8);  // k[b][m][k..k+8)
    }
    acc = __builtin_amdgcn_mfma_f32_16x16x32_bf16(af, bf, acc, 0, 0, 0);
  }
  // acc[r] = attn[c = quad*4+r][e = m]
  float logit_e = (m < NCLS) ? logits[(size_t)b * 16 + m] : 0.f;
  float sig = 1.f / (1.f + __expf(-logit_e));
  float corr[4];
#pragma unroll
  for (int r = 0; r < 4; ++r) {
    int c = quad * 4 + r;
    float diag = __shfl(acc[r], (lane & 48) + c, 64);  // attn[c][c] lives in same 16-lane group
    float a = acc[r] - diag;
    float av = (m < NCLS) ? fabsf(a) : 0.f;
    av = fmaxf(av, __shfl_xor(av, 1, 64));
    av = fmaxf(av, __shfl_xor(av, 2, 64));
    av = fmaxf(av, __shfl_xor(av, 4, 64));
    av = fmaxf(av, __shfl_xor(av, 8, 64));
    float v = (m < NCLS) ? (a / av) * sig : 0.f;
    v += __shfl_xor(v, 1, 64);
    v += __shfl_xor(v, 2, 64);
    v += __shfl_xor(v, 4, 64);
    v += __shfl_xor(v, 8, 64);
    corr[r] = v;
  }
  if (m == 0) {
#pragma unroll
    for (int r = 0; r < 4; ++r) {
      int c = quad * 4 + r;
      if (c < NCLS) {
        float lc = logits[(size_t)b * 16 + c];
        out[(size_t)b * NCLS + c] = lc + gamma[c] * corr[r];
      }
    }
  }
}

// ---------------- launch ----------------

extern "C" void kernel_launch(void* const* d_in, const int* in_sizes, int n_in,
                              void* d_out, int out_size, void* d_ws, size_t ws_size,
                              hipStream_t stream) {
  const float* features = (const float*)d_in[0];
  const float* W_proj   = (const float*)d_in[1];
  const float* b_proj   = (const float*)d_in[2];
  const float* bn_gamma = (const float*)d_in[3];
  const float* bn_beta  = (const float*)d_in[4];
  const float* W_qk     = (const float*)d_in[5];
  const float* gamma    = (const float*)d_in[6];
  const float* W_fc     = (const float*)d_in[7];
  const float* b_fc     = (const float*)d_in[8];
  float* out = (float*)d_out;

  char* ws = (char*)d_ws;
  unsigned short* featC   = (unsigned short*)ws;                  //  67,108,864 B
  unsigned short* hbuf    = (unsigned short*)(ws + 67108864);     //  67,108,864 B (bf16 h, in-place BN)
  unsigned short* WcatC   = (unsigned short*)(ws + 134217728);    //   8,912,896 B
  unsigned short* WqkC    = (unsigned short*)(ws + 143130624);    //   7,340,032 B
  unsigned short* qkC     = (unsigned short*)(ws + 150470656);    //  58,720,256 B (bf16 qk)
  float*          logitsB = (float*)(ws + 209190912);             //   1,048,576 B ([B,16] fp32)
  float*          colsum  = (float*)(ws + 210239488);             //       8,192 B
  float*          colsq   = (float*)(ws + 210247680);             //       8,192 B
  float*          scalev  = (float*)(ws + 210255872);             //       8,192 B
  float*          shiftv  = (float*)(ws + 210264064);             //       8,192 B (total 210,272,256)

  // zero BN accumulators (colsum+colsq adjacent) before GEMM1's fused stats
  hipMemsetAsync(colsum, 0, 16384, stream);

  // prep casts
  cast8_bf16<<<16384, 256, 0, stream>>>(features, featC, (BROWS * FDIM) / 8);
  build_wcat<<<NCAT, 256, 0, stream>>>(W_proj, W_fc, WcatC);
  cast8_bf16<<<1792, 256, 0, stream>>>(W_qk, WqkC, (QKN * FDIM) / 8);

  // GEMM1: bf16 h[B,2048] (+bias, +BN stats atomics) and fp32 logits[B,16] (+bias)
  gemm_bt<0><<<dim3(BROWS / 128, NCAT / 128), 256, 0, stream>>>(
      featC, WcatC, b_proj, b_fc, hbuf, logitsB, colsum, colsq,
      FDIM, FDIM, FDIM, FDIM);

  // BN finalize + in-place apply (relu) on bf16 h
  bn_finalize<<<8, 256, 0, stream>>>(colsum, colsq, bn_gamma, bn_beta, scalev, shiftv);
  bn_apply<<<16384, 256, 0, stream>>>(hbuf, scalev, shiftv);

  // GEMM2: bf16 qk[B,1792] = h @ W_qk^T
  gemm_bt<1><<<dim3(BROWS / 128, QKN / 128), 256, 0, stream>>>(
      hbuf, WqkC, nullptr, nullptr, qkC, nullptr, nullptr, nullptr,
      FDIM, FDIM, FDIM, QKN);

  // attention epilogue (one wave per row)
  attn_ep<<<BROWS / 4, 256, 0, stream>>>(qkC, logitsB, gamma, out);
}